// Round 5
// baseline (193.694 us; speedup 1.0000x reference)
//
#include <hip/hip_runtime.h>
#include <hip/hip_bf16.h>
#include <math.h>

typedef unsigned int uint;
typedef unsigned short ushort;
typedef __attribute__((ext_vector_type(8))) short short8;
typedef __attribute__((ext_vector_type(4))) float f32x4;

#define K_DIM 8192
#define ROWB 16384  // K_DIM * 2 bytes per row of XT / YT
#define N_TILE 78   // 32 XY + 36 XX-tri + 10 YY-tri (256x256 tiles)
#define S_SPLIT 3

// ws layout (bytes):
//   0        : double sums[4]           (xy, xx, yy)
//   256      : float  csx[2048]
//   8448     : float  csy[1024]
//   16384    : ushort XT[2048][8192]    centered x^T, bf16, swizzled (32 MB)
//   33570816 : ushort YT[1024][8192]    centered y^T, bf16, swizzled (16 MB)
//   50348032 : float  C[78][65536]      partial-C accumulators (19.5 MB)
// total = 70795264 B (proven to fit). Fallback if smaller.
//
// Global bf16 layout (NEW in R5): row m, K-tile t chunk (128 B) at t*128;
// within chunk: K-half kh (64 B) at kh*64; 16B unit u (u = (k%32)/8) stored
// at slot u ^ ((m>>1)&3). Stage is linear gload_lds; GEMM read applies the
// same XOR -> 2-way bank aliasing only (free).

__device__ __forceinline__ ushort f2bf(float f) {
  uint x = __float_as_uint(f);
  uint r = (x + 0x7fffu + ((x >> 16) & 1u)) >> 16;  // RTNE
  return (ushort)r;
}

__device__ __forceinline__ void async16(const void* g, void* l) {
  __builtin_amdgcn_global_load_lds(
      (const __attribute__((address_space(1))) unsigned int*)g,
      (__attribute__((address_space(3))) unsigned int*)l, 16, 0, 0);
}

#define BAR() asm volatile("s_barrier" ::: "memory")

__global__ __launch_bounds__(256) void zero_k(double* sums, float* csx, float* csy) {
  int t = threadIdx.x;
  if (t < 4) sums[t] = 0.0;
  for (int i = t; i < 2048; i += 256) csx[i] = 0.f;
  for (int i = t; i < 1024; i += 256) csy[i] = 0.f;
}

__global__ __launch_bounds__(256) void zeroC_k(float* C) {
  size_t base = ((size_t)blockIdx.x * 256 + threadIdx.x) * 16;
  float4 z = make_float4(0.f, 0.f, 0.f, 0.f);
#pragma unroll
  for (int j = 0; j < 4; j++) *(float4*)(C + base + j * 4) = z;
}

// 192 blocks: 0..127 -> x, 128..191 -> y
__global__ __launch_bounds__(256) void colsum_k(const float* __restrict__ x,
                                                const float* __restrict__ y,
                                                float* csx, float* csy) {
  int bid = blockIdx.x, t = threadIdx.x;
  const float* src; float* dst; int C, cb, rb;
  if (bid < 128) { src = x; dst = csx; C = 2048; cb = bid & 7; rb = bid >> 3; }
  else { int b = bid - 128; src = y; dst = csy; C = 1024; cb = b & 3; rb = b >> 2; }
  int col = cb * 256 + t;
  size_t base = (size_t)(rb * 512) * (size_t)C + (size_t)col;
  float s = 0.f;
  for (int r = 0; r < 512; r++) s += src[base + (size_t)r * C];
  atomicAdd(&dst[col], s);
}

// Center + transpose + bf16 + swizzle. 64x64 tiles.
__global__ __launch_bounds__(256) void centerT_k(const float* __restrict__ x,
                                                 const float* __restrict__ y,
                                                 const float* __restrict__ csx,
                                                 const float* __restrict__ csy,
                                                 ushort* XT, ushort* YT) {
  __shared__ float tile[64][65];
  int bid = blockIdx.x, t = threadIdx.x;
  const float* src; const float* cs; char* dst; int C, mt, kt;
  if (bid < 4096) { src = x; cs = csx; dst = (char*)XT; C = 2048; mt = bid >> 7; kt = bid & 127; }
  else { int b = bid - 4096; src = y; cs = csy; dst = (char*)YT; C = 1024; mt = b >> 7; kt = b & 127; }
  int m0 = mt * 64, k0 = kt * 64;

#pragma unroll
  for (int rep = 0; rep < 16; rep++) {
    int idx = rep * 256 + t;
    int kr = idx >> 6, mc = idx & 63;
    tile[kr][mc] = src[(size_t)(k0 + kr) * C + (size_t)(m0 + mc)];
  }
  __syncthreads();

  const float inv_n = 1.0f / 8192.0f;
#pragma unroll
  for (int rep = 0; rep < 2; rep++) {
    int uid = rep * 256 + t;
    int ml = uid >> 3, u = uid & 7;
    int m = m0 + ml;
    float mean = cs[m] * inv_n;
    uint wds[4];
#pragma unroll
    for (int j = 0; j < 4; j++) {
      float f0 = tile[u * 8 + 2 * j][ml] - mean;
      float f1 = tile[u * 8 + 2 * j + 1][ml] - mean;
      wds[j] = (uint)f2bf(f0) | ((uint)f2bf(f1) << 16);
    }
    // NEW swizzle: K-half kh = u>>2 at +kh*64; unit u&3 at slot (u&3)^((m>>1)&3)
    int kh = u >> 2, u4 = u & 3;
    size_t off = (size_t)m * ROWB + (size_t)(k0 >> 6) * 128 + (size_t)(kh * 64) +
                 (size_t)(((u4 ^ ((m >> 1) & 3))) << 4);
    uint4 v; v.x = wds[0]; v.y = wds[1]; v.z = wds[2]; v.w = wds[3];
    *(uint4*)(dst + off) = v;
  }
}

// tile in [0,78): <32 XY ; <68 XX-tri ; else YY-tri.
__device__ __forceinline__ void tile_decomp(int tile, int* m0, int* n0,
                                            int* which, int* diag) {
  if (tile < 32) { *m0 = (tile >> 2) * 256; *n0 = (tile & 3) * 256; *which = 0; *diag = 0; }
  else if (tile < 68) {
    int idx = tile - 32, ti = 0;
    while (idx >= 8 - ti) { idx -= 8 - ti; ti++; }
    *m0 = ti * 256; *n0 = (ti + idx) * 256; *which = 1; *diag = (idx == 0);
  } else {
    int idx = tile - 68, ti = 0;
    while (idx >= 4 - ti) { idx -= 4 - ti; ti++; }
    *m0 = ti * 256; *n0 = (ti + idx) * 256; *which = 2; *diag = (idx == 0);
  }
}

// Stage one 16KB half-unit (256 rows x 32 k of one matrix): 2 gload_lds/thread.
// LDS dest is wave-uniform base + lane*16 (verified: (lane>>2)*64+(lane&3)*16 == lane*16).
__device__ __forceinline__ void stage_unit(const char* gbase, int kt, int kh,
                                           char* ldst, int u2, int rr) {
  size_t gk = (size_t)kt * 128 + (size_t)(kh * 64) + (size_t)(u2 * 16);
#pragma unroll
  for (int c = 0; c < 2; c++) {
    int row = c * 128 + rr;
    async16(gbase + (size_t)row * ROWB + gk, ldst + row * 64 + u2 * 16);
  }
}

// 8-phase (4 phases x 2 K-halves per BK=64 K-tile) 256x256 GEMM, K-split x3.
// 234 blocks x 512 threads (8 waves, 2M x 4N; wave tile 128x64 = 8x4 frags).
// LDS 128KB: buf{0,1} x [A_k0|A_k1|B_k0|B_k1] x 16KB.
__global__ __launch_bounds__(512, 2) void gemm_split_k(const ushort* __restrict__ XT,
                                                       const ushort* __restrict__ YT,
                                                       float* __restrict__ Cbuf) {
  __shared__ char lds[131072];

  // T1: bijective chunked XCD swizzle over nwg=234 (q=29, r=2), tile-major
  int orig = blockIdx.x;
  int xcd = orig & 7, idx8 = orig >> 3;
  const int q = 234 / 8, r = 234 % 8;
  int off = (xcd < r) ? xcd * (q + 1) : r * (q + 1) + (xcd - r) * q;
  int wgid = off + idx8;
  int s = wgid / N_TILE, tile = wgid - s * N_TILE;

  int m0, n0, which, diag;
  tile_decomp(tile, &m0, &n0, &which, &diag);
  const char* Ab = (const char*)((which == 2) ? YT : XT);
  const char* Bb = (const char*)((which == 0) ? YT : (which == 1) ? (const ushort*)XT : YT);
  const char* Ag = Ab + (size_t)m0 * ROWB;
  const char* Bg = Bb + (size_t)n0 * ROWB;

  int k0 = (128 * s) / S_SPLIT;
  int k1 = (128 * (s + 1)) / S_SPLIT;
  int nst = k1 - k0;

  int t512 = threadIdx.x;
  int u2 = t512 & 3, rr = t512 >> 2;       // staging: 16B unit / row
  int w = t512 >> 6, lane = t512 & 63;
  int wm = (w >> 2) * 128, wn = (w & 3) * 64;  // 2x4 wave grid
  int lr = lane & 15, lk = lane >> 4;
  const int bregion = diag ? 0 : 32768;

  // Precomputed swizzled LDS byte offsets (without buf/kh component)
  int offA[8], offB[4];
#pragma unroll
  for (int mi = 0; mi < 8; mi++) {
    int row = wm + mi * 16 + lr;
    offA[mi] = row * 64 + ((lk ^ ((row >> 1) & 3)) << 4);
  }
#pragma unroll
  for (int nj = 0; nj < 4; nj++) {
    int row = wn + nj * 16 + lr;
    offB[nj] = row * 64 + ((lk ^ ((row >> 1) & 3)) << 4);
  }

  f32x4 acc[8][4];
#pragma unroll
  for (int i = 0; i < 8; i++)
#pragma unroll
    for (int j = 0; j < 4; j++)
      acc[i][j] = (f32x4){0.f, 0.f, 0.f, 0.f};

#define MPHASE(mq, kh, LOADB)                                                         \
  {                                                                                   \
    const char* la_ = lds + (cur << 16) + ((kh) << 14);                               \
    const char* lb_ = lds + (cur << 16) + bregion + ((kh) << 14);                     \
    short8 av[4];                                                                     \
    _Pragma("unroll")                                                                 \
    for (int j = 0; j < 4; j++) av[j] = *(const short8*)(la_ + offA[(mq) * 4 + j]);   \
    if (LOADB) {                                                                      \
      _Pragma("unroll")                                                               \
      for (int n = 0; n < 4; n++) bv[n] = *(const short8*)(lb_ + offB[n]);            \
    }                                                                                 \
    __builtin_amdgcn_s_setprio(1);                                                    \
    _Pragma("unroll")                                                                 \
    for (int j = 0; j < 4; j++)                                                       \
      _Pragma("unroll")                                                               \
      for (int n = 0; n < 4; n++)                                                     \
        acc[(mq) * 4 + j][n] =                                                        \
            __builtin_amdgcn_mfma_f32_16x16x32_bf16(av[j], bv[n], acc[(mq) * 4 + j][n], 0, 0, 0); \
    __builtin_amdgcn_s_setprio(0);                                                    \
  }

  // Prologue: tile0 fully + K-half0 of tile1 (nst >= 42 always)
  stage_unit(Ag, k0, 0, lds + 0, u2, rr);
  if (!diag) stage_unit(Bg, k0, 0, lds + 32768, u2, rr);
  stage_unit(Ag, k0, 1, lds + 16384, u2, rr);
  if (!diag) stage_unit(Bg, k0, 1, lds + 49152, u2, rr);
  stage_unit(Ag, k0 + 1, 0, lds + 65536, u2, rr);
  if (!diag) stage_unit(Bg, k0 + 1, 0, lds + 65536 + 32768, u2, rr);

  for (int t = 0; t < nst; ++t) {
    int cur = t & 1;
    int nxt = cur ^ 1;
    short8 bv[4];

    // ---- phase 1: stage A_k1(t+1); verify tile t; compute m0-3 x ks0 ----
    if (t + 1 < nst) stage_unit(Ag, k0 + t + 1, 1, lds + (nxt << 16) + 16384, u2, rr);
    if (t == nst - 1)
      asm volatile("s_waitcnt vmcnt(0)" ::: "memory");
    else if (diag)
      asm volatile("s_waitcnt vmcnt(4)" ::: "memory");
    else
      asm volatile("s_waitcnt vmcnt(6)" ::: "memory");
    BAR();
    MPHASE(0, 0, 1);
    BAR();

    // ---- phase 2: stage B_k1(t+1); compute m4-7 x ks0 (reuse bv) ----
    if (t + 1 < nst && !diag) stage_unit(Bg, k0 + t + 1, 1, lds + (nxt << 16) + 49152, u2, rr);
    BAR();
    MPHASE(1, 0, 0);
    BAR();

    // ---- phase 3: stage A_k0(t+2); compute m0-3 x ks1 ----
    if (t + 2 < nst) stage_unit(Ag, k0 + t + 2, 0, lds + (cur << 16), u2, rr);
    BAR();
    MPHASE(0, 1, 1);
    BAR();

    // ---- phase 4: stage B_k0(t+2); compute m4-7 x ks1 ----
    if (t + 2 < nst && !diag) stage_unit(Bg, k0 + t + 2, 0, lds + (cur << 16) + 32768, u2, rr);
    BAR();
    MPHASE(1, 1, 0);
    BAR();
  }
#undef MPHASE

  // Accumulate partial C. Bijection: w*8192 + frag*256 + e*64 + lane
  // (identical across the 3 K-split siblings -> same slot per logical element).
  float* Ct = Cbuf + (size_t)tile * 65536;
#pragma unroll
  for (int mi = 0; mi < 8; mi++)
#pragma unroll
    for (int nj = 0; nj < 4; nj++)
#pragma unroll
      for (int e = 0; e < 4; e++)
        atomicAdd(&Ct[w * 8192 + (mi * 4 + nj) * 256 + e * 64 + lane], acc[mi][nj][e]);
}

// 78*8 = 624 blocks: square+sum partial C with per-tile weights.
__global__ __launch_bounds__(256) void reduceC_k(const float* __restrict__ C, double* sums) {
  __shared__ double p[4];
  int bid = blockIdx.x, t = threadIdx.x;
  int tile = bid >> 3, seg = bid & 7;
  int m0, n0, which, diag;
  tile_decomp(tile, &m0, &n0, &which, &diag);
  double wgt = diag ? 1.0 : (which == 0 ? 1.0 : 2.0);

  const float* Ct = C + (size_t)tile * 65536 + (size_t)seg * 8192;
  double s = 0.0;
  for (int i = t * 4; i < 8192; i += 1024) {
    float4 v = *(const float4*)(Ct + i);
    s += (double)v.x * v.x + (double)v.y * v.y + (double)v.z * v.z + (double)v.w * v.w;
  }
  for (int off = 32; off; off >>= 1) s += __shfl_down(s, off, 64);
  if ((t & 63) == 0) p[t >> 6] = s;
  __syncthreads();
  if (t == 0) atomicAdd(&sums[which], wgt * (p[0] + p[1] + p[2] + p[3]));
}

// ---------------- Fallback path (no K-split), updated to new swizzle ----
__global__ __launch_bounds__(512, 2) void gemm_fro_k(const ushort* __restrict__ XT,
                                                     const ushort* __restrict__ YT,
                                                     double* sums) {
  __shared__ char lds[32768];
  __shared__ double part[8];
  char* ldsA = lds;
  char* ldsB = lds + 16384;

  int bid = blockIdx.x;
  const char* Ab; const char* Bb; int m0, n0, slot; double wgt;
  if (bid < 128) {
    int mt = bid >> 3, nt = bid & 7;
    Ab = (const char*)XT; Bb = (const char*)YT;
    m0 = mt * 128; n0 = nt * 128; wgt = 1.0; slot = 0;
  } else if (bid < 264) {
    int idx = bid - 128; int ti = 0;
    while (idx >= 16 - ti) { idx -= 16 - ti; ti++; }
    int tj = ti + idx;
    Ab = (const char*)XT; Bb = (const char*)XT;
    m0 = ti * 128; n0 = tj * 128; wgt = (ti == tj) ? 1.0 : 2.0; slot = 1;
  } else {
    int idx = bid - 264; int ti = 0;
    while (idx >= 8 - ti) { idx -= 8 - ti; ti++; }
    int tj = ti + idx;
    Ab = (const char*)YT; Bb = (const char*)YT;
    m0 = ti * 128; n0 = tj * 128; wgt = (ti == tj) ? 1.0 : 2.0; slot = 2;
  }

  int t = threadIdx.x;
  int row8 = t >> 3;
  int u = t & 7;
  int w = t >> 6;
  int lane = t & 63;
  int wm = (w >> 2) * 64, wn = (w & 3) * 32;
  int lr = lane & 15, lk = lane >> 4;

  f32x4 acc[4][2];
#pragma unroll
  for (int i = 0; i < 4; i++)
#pragma unroll
    for (int j = 0; j < 2; j++)
      acc[i][j] = (f32x4){0.f, 0.f, 0.f, 0.f};

  const size_t abase = (size_t)m0 * ROWB + (size_t)(u * 16);
  const size_t bbase = (size_t)n0 * ROWB + (size_t)(u * 16);

  for (int s = 0; s < K_DIM / 64; s++) {
    __syncthreads();
    size_t koff = (size_t)s * 128;
#pragma unroll
    for (int c = 0; c < 2; c++) {
      int row = c * 64 + row8;
      async16(Ab + abase + (size_t)row * ROWB + koff, ldsA + row * 128 + u * 16);
      async16(Bb + bbase + (size_t)row * ROWB + koff, ldsB + row * 128 + u * 16);
    }
    __syncthreads();

#pragma unroll
    for (int ks = 0; ks < 2; ks++) {
      short8 a[4], b[2];
#pragma unroll
      for (int mi = 0; mi < 4; mi++) {
        int row = wm + mi * 16 + lr;
        int ku = ks * 4 + lk;
        a[mi] = *(const short8*)(ldsA + row * 128 + ((ku >> 2) << 6) +
                                 (((ku & 3) ^ ((row >> 1) & 3)) << 4));
      }
#pragma unroll
      for (int nj = 0; nj < 2; nj++) {
        int row = wn + nj * 16 + lr;
        int ku = ks * 4 + lk;
        b[nj] = *(const short8*)(ldsB + row * 128 + ((ku >> 2) << 6) +
                                 (((ku & 3) ^ ((row >> 1) & 3)) << 4));
      }
#pragma unroll
      for (int mi = 0; mi < 4; mi++)
#pragma unroll
        for (int nj = 0; nj < 2; nj++)
          acc[mi][nj] = __builtin_amdgcn_mfma_f32_16x16x32_bf16(a[mi], b[nj], acc[mi][nj], 0, 0, 0);
    }
  }

  double local = 0.0;
#pragma unroll
  for (int mi = 0; mi < 4; mi++)
#pragma unroll
    for (int nj = 0; nj < 2; nj++)
#pragma unroll
      for (int e = 0; e < 4; e++) {
        double v = (double)acc[mi][nj][e];
        local += v * v;
      }

  for (int off = 32; off; off >>= 1) local += __shfl_down(local, off, 64);
  if (lane == 0) part[w] = local;
  __syncthreads();
  if (t == 0) {
    double tot = 0.0;
#pragma unroll
    for (int i = 0; i < 8; i++) tot += part[i];
    atomicAdd(&sums[slot], wgt * tot);
  }
}

__global__ void finalize_k(const double* sums, float* out) {
  double xy = sums[0], xx = sums[1], yy = sums[2];
  out[0] = (float)(xy / (sqrt(xx * yy) + 1e-8));
}

extern "C" void kernel_launch(void* const* d_in, const int* in_sizes, int n_in,
                              void* d_out, int out_size, void* d_ws, size_t ws_size,
                              hipStream_t stream) {
  (void)in_sizes; (void)n_in; (void)out_size;
  const float* x = (const float*)d_in[0];
  const float* y = (const float*)d_in[1];
  float* out = (float*)d_out;
  char* ws = (char*)d_ws;
  double* sums = (double*)ws;
  float* csx = (float*)(ws + 256);
  float* csy = (float*)(ws + 8448);
  ushort* XT = (ushort*)(ws + 16384);
  ushort* YT = (ushort*)(ws + 33570816);
  float* Cbuf = (float*)(ws + 50348032);
  const size_t NEED = 70795264;

  zero_k<<<1, 256, 0, stream>>>(sums, csx, csy);
  colsum_k<<<192, 256, 0, stream>>>(x, y, csx, csy);
  centerT_k<<<6144, 256, 0, stream>>>(x, y, csx, csy, XT, YT);
  if (ws_size >= NEED) {
    zeroC_k<<<1248, 256, 0, stream>>>(Cbuf);
    gemm_split_k<<<N_TILE * S_SPLIT, 512, 0, stream>>>(XT, YT, Cbuf);
    reduceC_k<<<N_TILE * 8, 256, 0, stream>>>(Cbuf, sums);
  } else {
    gemm_fro_k<<<300, 512, 0, stream>>>(XT, YT, sums);
  }
  finalize_k<<<1, 1, 0, stream>>>(sums, out);
}

// Round 6
// 177.113 us; speedup vs baseline: 1.0936x; 1.0936x over previous
//
#include <hip/hip_runtime.h>
#include <hip/hip_bf16.h>
#include <math.h>

typedef unsigned int uint;
typedef unsigned short ushort;
typedef __attribute__((ext_vector_type(4))) int i32x4;

#define K_DIM 8192
#define ROW8 8192   // bytes per row of XT8 / YT8 (i8)
#define N_TILE 78   // 32 XY + 36 XX-tri + 10 YY-tri (256x256 tiles)
#define S_SPLIT 3
#define NKT 64      // K-tiles of BK=128

// ws layout (bytes):
//   0        : double sums[4]           (xy, xx, yy)
//   64       : uint   amax[2]           (absmax bits of x, y)
//   256      : float  csx[2048]
//   8448     : float  csy[1024]
//   16384    : char   XT8[2048][8192]   centered x^T, i8, swizzled (16 MB)
//   16793600 : char   YT8[1024][8192]   centered y^T, i8, swizzled (8 MB)
//   25182208 : float  C[78][65536]      partial-C accumulators (19.5 MB)
// total = 44693632 B (< 70.8 MB proven available in R3-R5).
//
// Global i8 layout: row m, K-tile t chunk (128 B) at t*128; 16B unit
// u = (k%128)/16 stored at slot u ^ (m&7) (R1-proven conflict-free pattern).
// Stage is linear gload_lds; GEMM read applies the same XOR.

__device__ __forceinline__ void async16(const void* g, void* l) {
  __builtin_amdgcn_global_load_lds(
      (const __attribute__((address_space(1))) unsigned int*)g,
      (__attribute__((address_space(3))) unsigned int*)l, 16, 0, 0);
}

__device__ __forceinline__ float mk_scale(uint bits) {
  // identical in centerT and gemm: scale = 127 / (absmax(raw) + mean margin)
  return 127.0f / (__uint_as_float(bits) + 0.06f);
}

__global__ __launch_bounds__(256) void zero_k(double* sums, uint* amax,
                                              float* csx, float* csy) {
  int t = threadIdx.x;
  if (t < 4) sums[t] = 0.0;
  if (t < 2) amax[t] = 0u;
  for (int i = t; i < 2048; i += 256) csx[i] = 0.f;
  for (int i = t; i < 1024; i += 256) csy[i] = 0.f;
}

__global__ __launch_bounds__(256) void zeroC_k(float* C) {
  size_t base = ((size_t)blockIdx.x * 256 + threadIdx.x) * 16;
  float4 z = make_float4(0.f, 0.f, 0.f, 0.f);
#pragma unroll
  for (int j = 0; j < 4; j++) *(float4*)(C + base + j * 4) = z;
}

// 192 blocks: 0..127 -> x, 128..191 -> y. Column sums + global absmax.
__global__ __launch_bounds__(256) void colsum_k(const float* __restrict__ x,
                                                const float* __restrict__ y,
                                                float* csx, float* csy,
                                                uint* amax) {
  __shared__ float am4[4];
  int bid = blockIdx.x, t = threadIdx.x;
  const float* src; float* dst; uint* adst; int C, cb, rb;
  if (bid < 128) { src = x; dst = csx; adst = amax + 0; C = 2048; cb = bid & 7; rb = bid >> 3; }
  else { int b = bid - 128; src = y; dst = csy; adst = amax + 1; C = 1024; cb = b & 3; rb = b >> 2; }
  int col = cb * 256 + t;
  size_t base = (size_t)(rb * 512) * (size_t)C + (size_t)col;
  float s = 0.f, am = 0.f;
  for (int r = 0; r < 512; r++) {
    float v = src[base + (size_t)r * C];
    s += v;
    am = fmaxf(am, fabsf(v));
  }
  atomicAdd(&dst[col], s);
  for (int off = 32; off; off >>= 1) am = fmaxf(am, __shfl_down(am, off, 64));
  if ((t & 63) == 0) am4[t >> 6] = am;
  __syncthreads();
  if (t == 0) {
    am = fmaxf(fmaxf(am4[0], am4[1]), fmaxf(am4[2], am4[3]));
    atomicMax(adst, __float_as_uint(am));
  }
}

// Center + transpose + i8-quantize + swizzle. 64x64 tiles.
// blocks 0..4095 -> x (mt=bid>>7, kt=bid&127), 4096..6143 -> y.
__global__ __launch_bounds__(256) void centerT_k(const float* __restrict__ x,
                                                 const float* __restrict__ y,
                                                 const float* __restrict__ csx,
                                                 const float* __restrict__ csy,
                                                 const uint* __restrict__ amax,
                                                 char* XT8, char* YT8) {
  __shared__ float tile[64][65];
  int bid = blockIdx.x, t = threadIdx.x;
  const float* src; const float* cs; char* dst; int C, mt, kt; float sc;
  if (bid < 4096) { src = x; cs = csx; dst = XT8; C = 2048; mt = bid >> 7; kt = bid & 127; sc = mk_scale(amax[0]); }
  else { int b = bid - 4096; src = y; cs = csy; dst = YT8; C = 1024; mt = b >> 7; kt = b & 127; sc = mk_scale(amax[1]); }
  int m0 = mt * 64, k0 = kt * 64;

#pragma unroll
  for (int rep = 0; rep < 16; rep++) {
    int idx = rep * 256 + t;
    int kr = idx >> 6, mc = idx & 63;
    tile[kr][mc] = src[(size_t)(k0 + kr) * C + (size_t)(m0 + mc)];
  }
  __syncthreads();

  const float inv_n = 1.0f / 8192.0f;
  int ml = t >> 2, ul = t & 3;   // m within tile / 16-k unit within 64k
  int m = m0 + ml;
  float mean = cs[m] * inv_n;
  uint wd[4];
#pragma unroll
  for (int jw = 0; jw < 4; jw++) {
    uint wv = 0;
#pragma unroll
    for (int b = 0; b < 4; b++) {
      int kl = ul * 16 + jw * 4 + b;
      float f = (tile[kl][ml] - mean) * sc;
      int q = __float2int_rn(f);
      q = max(-127, min(127, q));
      wv |= ((uint)(q & 0xFF)) << (8 * b);
    }
    wd[jw] = wv;
  }
  int kglob = k0 + ul * 16;
  size_t off = (size_t)m * ROW8 + (size_t)(kglob >> 7) * 128 +
               (size_t)((((kglob >> 4) & 7) ^ (m & 7)) << 4);
  uint4 v; v.x = wd[0]; v.y = wd[1]; v.z = wd[2]; v.w = wd[3];
  *(uint4*)(dst + off) = v;
}

// tile in [0,78): <32 XY ; <68 XX-tri ; else YY-tri.
__device__ __forceinline__ void tile_decomp(int tile, int* m0, int* n0,
                                            int* which, int* diag) {
  if (tile < 32) { *m0 = (tile >> 2) * 256; *n0 = (tile & 3) * 256; *which = 0; *diag = 0; }
  else if (tile < 68) {
    int idx = tile - 32, ti = 0;
    while (idx >= 8 - ti) { idx -= 8 - ti; ti++; }
    *m0 = ti * 256; *n0 = (ti + idx) * 256; *which = 1; *diag = (idx == 0);
  } else {
    int idx = tile - 68, ti = 0;
    while (idx >= 4 - ti) { idx -= 4 - ti; ti++; }
    *m0 = ti * 256; *n0 = (ti + idx) * 256; *which = 2; *diag = (idx == 0);
  }
}

// i8 K-split GEMM: 78 tiles x 3 K-chunks = 234 blocks x 512 threads (8 waves).
// Tile 256x256, BK=128, double-buffered 128 KiB LDS, 2-phase (R3, fastest).
// mfma_i32_16x16x64_i8; wave grid 2M x 4N (wave tile 128x64 = 8x4 frags).
// Same per-K-tile resource profile as bf16 BK=64, but half the K-tiles.
__global__ __launch_bounds__(512, 2) void gemm_i8_k(const char* __restrict__ XT8,
                                                    const char* __restrict__ YT8,
                                                    const uint* __restrict__ amax,
                                                    float* __restrict__ Cbuf) {
  __shared__ char lds[131072];  // 2 bufs x (A 32K + B 32K)

  // T1: bijective chunked XCD swizzle over nwg=234 (q=29, r=2), tile-major
  int orig = blockIdx.x;
  int xcd = orig & 7, idx8 = orig >> 3;
  const int q = 234 / 8, r = 234 % 8;
  int off = (xcd < r) ? xcd * (q + 1) : r * (q + 1) + (xcd - r) * q;
  int wgid = off + idx8;
  int s = wgid / N_TILE, tile = wgid - s * N_TILE;

  int m0, n0, which, diag;
  tile_decomp(tile, &m0, &n0, &which, &diag);
  const char* Ab = (which == 2) ? YT8 : XT8;
  const char* Bb = (which == 0) ? YT8 : (which == 1) ? XT8 : YT8;
  const char* Ag = Ab + (size_t)m0 * ROW8;
  const char* Bg = Bb + (size_t)n0 * ROW8;
  float sA = mk_scale(amax[(which == 2) ? 1 : 0]);
  float sB = mk_scale(amax[(which == 0) ? 1 : (which == 1) ? 0 : 1]);
  float invs = 1.0f / (sA * sB);

  int k0t = (NKT * s) / S_SPLIT;        // 0,21,42
  int k1t = (NKT * (s + 1)) / S_SPLIT;  // 21,42,64
  int nst = k1t - k0t;

  int t = threadIdx.x;
  int u = t & 7;          // 16B unit within a row's 128B K-tile chunk
  int rr = t >> 3;        // staging row 0..63 (+c*64)
  int w = t >> 6;
  int lane = t & 63;
  int wm = (w >> 2) * 128, wn = (w & 3) * 64;  // 2x4 wave grid
  int lr = lane & 15, lk = lane >> 4;
  const bool doB = !diag;

  i32x4 acc[8][4];
#pragma unroll
  for (int i = 0; i < 8; i++)
#pragma unroll
    for (int j = 0; j < 4; j++)
      acc[i][j] = (i32x4){0, 0, 0, 0};

  const size_t abase = (size_t)(u * 16);

#define STAGE(buf, kt)                                                              \
  {                                                                                 \
    size_t koff = (size_t)(kt) * 128 + abase;                                       \
    char* la_ = lds + (buf) * 65536;                                                \
    char* lb_ = la_ + 32768;                                                        \
    _Pragma("unroll")                                                               \
    for (int c = 0; c < 4; c++) {                                                   \
      int row = c * 64 + rr;                                                        \
      async16(Ag + (size_t)row * ROW8 + koff, la_ + row * 128 + u * 16);            \
      if (doB)                                                                      \
        async16(Bg + (size_t)row * ROW8 + koff, lb_ + row * 128 + u * 16);          \
    }                                                                               \
  }

  STAGE(0, k0t);
  __syncthreads();  // buf0 staged

  for (int i = 0; i < nst; ++i) {
    int cur = i & 1;
    if (i + 1 < nst) STAGE(cur ^ 1, k0t + i + 1);  // prefetch overlaps compute

    const char* la = lds + cur * 65536;
    const char* lb = doB ? (la + 32768) : la;
#pragma unroll
    for (int ks = 0; ks < 2; ks++) {
      int ku = ks * 4 + lk;
      i32x4 a[8], b[4];
#pragma unroll
      for (int mi = 0; mi < 8; mi++) {
        int row = wm + mi * 16 + lr;
        a[mi] = *(const i32x4*)(la + row * 128 + ((ku ^ (row & 7)) << 4));
      }
#pragma unroll
      for (int nj = 0; nj < 4; nj++) {
        int row = wn + nj * 16 + lr;
        b[nj] = *(const i32x4*)(lb + row * 128 + ((ku ^ (row & 7)) << 4));
      }
#pragma unroll
      for (int mi = 0; mi < 8; mi++)
#pragma unroll
        for (int nj = 0; nj < 4; nj++)
          acc[mi][nj] = __builtin_amdgcn_mfma_i32_16x16x64_i8(a[mi], b[nj], acc[mi][nj], 0, 0, 0);
    }
    __syncthreads();  // drains prefetch + LDS reads; buf swap safe
  }
#undef STAGE

  // Dequantized partial C. Bijection: w*8192 + frag*256 + e*64 + lane
  // (identical across the 3 K-split siblings -> same slot per logical element).
  float* Ct = Cbuf + (size_t)tile * 65536;
#pragma unroll
  for (int mi = 0; mi < 8; mi++)
#pragma unroll
    for (int nj = 0; nj < 4; nj++)
#pragma unroll
      for (int e = 0; e < 4; e++)
        atomicAdd(&Ct[w * 8192 + (mi * 4 + nj) * 256 + e * 64 + lane],
                  (float)acc[mi][nj][e] * invs);
}

// 78*8 = 624 blocks: square+sum partial C with per-tile weights.
__global__ __launch_bounds__(256) void reduceC_k(const float* __restrict__ C, double* sums) {
  __shared__ double p[4];
  int bid = blockIdx.x, t = threadIdx.x;
  int tile = bid >> 3, seg = bid & 7;
  int m0, n0, which, diag;
  tile_decomp(tile, &m0, &n0, &which, &diag);
  double wgt = diag ? 1.0 : (which == 0 ? 1.0 : 2.0);

  const float* Ct = C + (size_t)tile * 65536 + (size_t)seg * 8192;
  double s = 0.0;
  for (int i = t * 4; i < 8192; i += 1024) {
    float4 v = *(const float4*)(Ct + i);
    s += (double)v.x * v.x + (double)v.y * v.y + (double)v.z * v.z + (double)v.w * v.w;
  }
  for (int off = 32; off; off >>= 1) s += __shfl_down(s, off, 64);
  if ((t & 63) == 0) p[t >> 6] = s;
  __syncthreads();
  if (t == 0) atomicAdd(&sums[which], wgt * (p[0] + p[1] + p[2] + p[3]));
}

__global__ void finalize_k(const double* sums, float* out) {
  double xy = sums[0], xx = sums[1], yy = sums[2];
  out[0] = (float)(xy / (sqrt(xx * yy) + 1e-8));
}

extern "C" void kernel_launch(void* const* d_in, const int* in_sizes, int n_in,
                              void* d_out, int out_size, void* d_ws, size_t ws_size,
                              hipStream_t stream) {
  (void)in_sizes; (void)n_in; (void)out_size; (void)ws_size;
  const float* x = (const float*)d_in[0];
  const float* y = (const float*)d_in[1];
  float* out = (float*)d_out;
  char* ws = (char*)d_ws;
  double* sums = (double*)ws;
  uint* amax = (uint*)(ws + 64);
  float* csx = (float*)(ws + 256);
  float* csy = (float*)(ws + 8448);
  char* XT8 = ws + 16384;
  char* YT8 = ws + 16793600;
  float* Cbuf = (float*)(ws + 25182208);

  zero_k<<<1, 256, 0, stream>>>(sums, amax, csx, csy);
  zeroC_k<<<1248, 256, 0, stream>>>(Cbuf);
  colsum_k<<<192, 256, 0, stream>>>(x, y, csx, csy, amax);
  centerT_k<<<6144, 256, 0, stream>>>(x, y, csx, csy, amax, XT8, YT8);
  gemm_i8_k<<<N_TILE * S_SPLIT, 512, 0, stream>>>(XT8, YT8, amax, Cbuf);
  reduceC_k<<<N_TILE * 8, 256, 0, stream>>>(Cbuf, sums);
  finalize_k<<<1, 1, 0, stream>>>(sums, out);
}